// Round 1
// baseline (150.222 us; speedup 1.0000x reference)
//
#include <hip/hip_runtime.h>

#define NN 62      // nodes per graph
#define NP 64      // padded row stride
#define NBATCH 1024
#define IN_CH 5
#define HID 64
#define OUT_CH 3
#define NTRIL 1953

// ---------------------------------------------------------------------------
// k1a: build A = D^-1/2 W D^-1/2 (padded 62x64, pad cols zero) into Ag
// ---------------------------------------------------------------------------
__global__ __launch_bounds__(256) void build_A(const float* __restrict__ p,
                                               float* __restrict__ Ag) {
    __shared__ float sW[NN * NP];
    __shared__ float sDinv[NN];
    const int t = threadIdx.x;

    for (int i = t; i < NN * NP; i += 256) sW[i] = 0.f;
    __syncthreads();

    // scatter tril vector into symmetric W
    for (int i = t; i < NTRIL; i += 256) {
        int r = (int)((sqrtf(8.f * (float)i + 1.f) - 1.f) * 0.5f);
        while (r * (r + 1) / 2 > i) --r;
        while ((r + 1) * (r + 2) / 2 <= i) ++r;
        int c = i - r * (r + 1) / 2;
        float v = p[i];
        sW[r * NP + c] = v;
        sW[c * NP + r] = v;
    }
    __syncthreads();

    if (t < NN) {
        float s = 0.f;
        for (int j = 0; j < NN; ++j) s += fabsf(sW[t * NP + j]);
        sDinv[t] = (s > 0.f) ? (1.0f / sqrtf(s)) : 0.f;
    }
    __syncthreads();

    for (int i = t; i < NN * NP; i += 256) {
        int n = i >> 6, j = i & 63;
        Ag[i] = (j < NN) ? sDinv[n] * sW[i] * sDinv[j] : 0.f;
    }
}

// ---------------------------------------------------------------------------
// k1b: A2 = A @ A (one block per output row; pad cols come out 0 since A pads 0)
// ---------------------------------------------------------------------------
__global__ __launch_bounds__(64) void build_A2(const float* __restrict__ Ag,
                                               float* __restrict__ A2g) {
    __shared__ float sA[NN * NP];
    const int lane = threadIdx.x;
    const int n = blockIdx.x;
    const float4* Av = (const float4*)Ag;
    float4* sAv = (float4*)sA;
    for (int i = lane; i < NN * NP / 4; i += 64) sAv[i] = Av[i];
    __syncthreads();

    float a0 = 0.f, a1 = 0.f;
    for (int k = 0; k < NN; k += 2) {
        a0 += sA[n * NP + k] * sA[k * NP + lane];
        a1 += sA[n * NP + k + 1] * sA[(k + 1) * NP + lane];
    }
    A2g[n * NP + lane] = a0 + a1;
}

// ---------------------------------------------------------------------------
// k2: full network, one wave (64 lanes) per graph; lane = hidden channel
// ---------------------------------------------------------------------------
__global__ __launch_bounds__(64, 1) void graph_net(
    const float* __restrict__ x, const float* __restrict__ A2g,
    const float* __restrict__ w1, const float* __restrict__ b1,
    const float* __restrict__ w2, const float* __restrict__ b2,
    const float* __restrict__ wfc, const float* __restrict__ bfc,
    float* __restrict__ out) {
    __shared__ float sA2[NN * NP];   // A^2, padded, symmetric
    __shared__ float sX[NN * 8];     // input features, stride 8
    __shared__ float sY1[NN * 8];    // A2 @ X
    __shared__ float sH1[NN * NP];   // relu layer-1 output
    __shared__ float sPool[NP];

    const int g = blockIdx.x;
    const int lane = threadIdx.x;

    // stage A2 into LDS (16B vectors)
    {
        const float4* src = (const float4*)A2g;
        float4* dst = (float4*)sA2;
        for (int i = lane; i < NN * NP / 4; i += 64) dst[i] = src[i];
    }
    // stage X
    {
        const float* xg = x + (size_t)g * (NN * IN_CH);
        for (int i = lane; i < NN * IN_CH; i += 64)
            sX[(i / IN_CH) * 8 + (i % IN_CH)] = xg[i];
    }
    // per-lane weights
    float w1r[IN_CH];
#pragma unroll
    for (int c = 0; c < IN_CH; ++c) w1r[c] = w1[lane * IN_CH + c];
    const float b1r = b1[lane];
    const float b2r = b2[lane];
    float w2r[HID];
    {
        const float4* w2v = (const float4*)w2;
#pragma unroll
        for (int i = 0; i < 16; ++i) {
            float4 v = w2v[lane * 16 + i];
            w2r[4 * i + 0] = v.x; w2r[4 * i + 1] = v.y;
            w2r[4 * i + 2] = v.z; w2r[4 * i + 3] = v.w;
        }
    }
    __syncthreads();

    // ---- Y1 = A2 @ X  (lane = node row; A2 symmetric -> read column, stride-1)
    if (lane < NN) {
        float acc[IN_CH] = {0.f, 0.f, 0.f, 0.f, 0.f};
        for (int k = 0; k < NN; ++k) {
            float a = sA2[k * NP + lane];  // = A2[lane][k]
#pragma unroll
            for (int c = 0; c < IN_CH; ++c) acc[c] += a * sX[k * 8 + c];
        }
#pragma unroll
        for (int c = 0; c < IN_CH; ++c) sY1[lane * 8 + c] = acc[c];
    }
    __syncthreads();

    // ---- H1[n][lane] = relu(b1 + sum_c Y1[n][c] * W1[lane][c])
    for (int n = 0; n < NN; ++n) {
        float v = b1r;
#pragma unroll
        for (int c = 0; c < IN_CH; ++c) v += sY1[n * 8 + c] * w1r[c];
        sH1[n * NP + lane] = fmaxf(v, 0.f);
    }
    __syncthreads();

    // ---- G[n] = sum_m H1[n][m] * W2[lane][m]   (H1 row broadcast, b128)
    float G[NP];
#pragma unroll 2
    for (int n = 0; n < NN; ++n) {
        const float4* hr = (const float4*)(sH1 + n * NP);
        float a0 = 0.f, a1 = 0.f, a2 = 0.f, a3 = 0.f;
#pragma unroll
        for (int i = 0; i < 16; ++i) {
            float4 h4 = hr[i];
            a0 += h4.x * w2r[4 * i + 0];
            a1 += h4.y * w2r[4 * i + 1];
            a2 += h4.z * w2r[4 * i + 2];
            a3 += h4.w * w2r[4 * i + 3];
        }
        G[n] = (a0 + a1) + (a2 + a3);
    }
    G[62] = 0.f;
    G[63] = 0.f;

    // ---- H2[n][lane] = relu(b2 + sum_k A2[n][k] * G[k]); pool over n on the fly
    float pooled = 0.f;
#pragma unroll 2
    for (int n = 0; n < NN; ++n) {
        const float4* ar = (const float4*)(sA2 + n * NP);
        float a0 = 0.f, a1 = 0.f, a2 = 0.f, a3 = 0.f;
#pragma unroll
        for (int i = 0; i < 16; ++i) {
            float4 a4 = ar[i];
            a0 += a4.x * G[4 * i + 0];
            a1 += a4.y * G[4 * i + 1];
            a2 += a4.z * G[4 * i + 2];
            a3 += a4.w * G[4 * i + 3];
        }
        pooled += fmaxf(b2r + (a0 + a1) + (a2 + a3), 0.f);
    }
    sPool[lane] = pooled;
    __syncthreads();

    // ---- out[g] = pooled @ wfc^T + bfc
    if (lane < OUT_CH) {
        float v = bfc[lane];
        const float* wr = wfc + lane * HID;
        for (int o = 0; o < HID; ++o) v += sPool[o] * wr[o];
        out[g * OUT_CH + lane] = v;
    }
}

// ---------------------------------------------------------------------------
extern "C" void kernel_launch(void* const* d_in, const int* in_sizes, int n_in,
                              void* d_out, int out_size, void* d_ws, size_t ws_size,
                              hipStream_t stream) {
    const float* x   = (const float*)d_in[0];
    // d_in[1] = edge_index, d_in[2] = batch: structure is fixed/deterministic -> unused
    const float* ewp = (const float*)d_in[3];
    const float* w1  = (const float*)d_in[4];
    const float* b1  = (const float*)d_in[5];
    const float* w2  = (const float*)d_in[6];
    const float* b2  = (const float*)d_in[7];
    const float* wfc = (const float*)d_in[8];
    const float* bfc = (const float*)d_in[9];
    float* out = (float*)d_out;

    float* Ag  = (float*)d_ws;          // 62*64 floats
    float* A2g = Ag + NN * NP;          // 62*64 floats

    build_A<<<1, 256, 0, stream>>>(ewp, Ag);
    build_A2<<<NN, 64, 0, stream>>>(Ag, A2g);
    graph_net<<<NBATCH, 64, 0, stream>>>(x, A2g, w1, b1, w2, b2, wfc, bfc, out);
}

// Round 2
// 147.648 us; speedup vs baseline: 1.0174x; 1.0174x over previous
//
#include <hip/hip_runtime.h>

#define NN 62      // nodes per graph
#define NP 64      // padded row stride
#define NBATCH 1024
#define IN_CH 5
#define HID 64
#define OUT_CH 3
#define NTRIL 1953
#define GT_STRIDE 68   // 68 % 32 == 4 -> b128 at lane*68 banks like contiguous (conflict-free)

// ---------------------------------------------------------------------------
// setup: 62 blocks x 64 threads; every block rebuilds A = D^-1/2 W D^-1/2 in
// LDS (redundant, cheap), block n writes row n of A2 = A@A (64-wide, pad 0).
// ---------------------------------------------------------------------------
__global__ __launch_bounds__(64) void setup_A2(const float* __restrict__ p,
                                               float* __restrict__ A2g) {
    __shared__ float sA[NN * NP];
    __shared__ float sDinv[NN];
    const int lane = threadIdx.x;
    const int n = blockIdx.x;

    for (int i = lane; i < NN * NP; i += 64) sA[i] = 0.f;
    __syncthreads();

    for (int i = lane; i < NTRIL; i += 64) {
        int r = (int)((sqrtf(8.f * (float)i + 1.f) - 1.f) * 0.5f);
        while (r * (r + 1) / 2 > i) --r;
        while ((r + 1) * (r + 2) / 2 <= i) ++r;
        int c = i - r * (r + 1) / 2;
        float v = p[i];
        sA[r * NP + c] = v;
        sA[c * NP + r] = v;
    }
    __syncthreads();

    if (lane < NN) {
        float s = 0.f;
        for (int j = 0; j < NN; ++j) s += fabsf(sA[lane * NP + j]);
        sDinv[lane] = (s > 0.f) ? (1.0f / sqrtf(s)) : 0.f;
    }
    __syncthreads();

    for (int i = lane; i < NN * NP; i += 64) {
        int r = i >> 6, c = i & 63;
        float dc = (c < NN) ? sDinv[c] : 0.f;
        sA[i] = sDinv[r] * sA[i] * dc;   // pad cols stay 0
    }
    __syncthreads();

    float acc = 0.f;
    for (int k = 0; k < NN; ++k)
        acc += sA[n * NP + k] * sA[k * NP + lane];
    A2g[n * NP + lane] = acc;            // lane>=62 -> 0 (A pad cols are 0)
}

// ---------------------------------------------------------------------------
// main: 1024 blocks x 256 threads = 4 waves/graph (node strips of 16).
// lane = hidden channel. A2 (batch-invariant) read via wave-uniform scalar
// loads from global in hop-2; G round-trips LDS once (transposed) then lives
// in registers.
// ---------------------------------------------------------------------------
__global__ __launch_bounds__(256, 4) void graph_net(
    const float* __restrict__ x, const float* __restrict__ A2g,
    const float* __restrict__ w1, const float* __restrict__ b1,
    const float* __restrict__ w2, const float* __restrict__ b2,
    const float* __restrict__ wfc, const float* __restrict__ bfc,
    float* __restrict__ out) {
    __shared__ float sX[NN * 8];
    __shared__ float sY1[NN * 8];
    __shared__ float sH1[NN * NP];
    __shared__ float sGT[NP * GT_STRIDE];
    __shared__ float sPoolW[4 * NP];

    const int t = threadIdx.x;
    const int lane = t & 63;
    const int w = __builtin_amdgcn_readfirstlane(t >> 6);  // wave-uniform
    const int g = blockIdx.x;

    // stage X (62x5, row stride 8)
    {
        const float* xg = x + (size_t)g * (NN * IN_CH);
        for (int i = t; i < NN * IN_CH; i += 256)
            sX[(i / IN_CH) * 8 + (i % IN_CH)] = xg[i];
    }

    // per-lane weights (same rows in every wave; L1-served)
    float w1r[IN_CH];
#pragma unroll
    for (int c = 0; c < IN_CH; ++c) w1r[c] = w1[lane * IN_CH + c];
    const float b1r = b1[lane];
    const float b2r = b2[lane];
    float w2r[HID];
    {
        const float4* w2v = (const float4*)w2;
#pragma unroll
        for (int i = 0; i < 16; ++i) {
            float4 v = w2v[lane * 16 + i];
            w2r[4 * i + 0] = v.x; w2r[4 * i + 1] = v.y;
            w2r[4 * i + 2] = v.z; w2r[4 * i + 3] = v.w;
        }
    }
    __syncthreads();

    // ---- Y1 = A2 @ X : thread (n = t>>2, q = t&3) partial over k ≡ q (mod 4)
    {
        const int n = t >> 2;
        const int q = t & 3;
        float acc[IN_CH] = {0.f, 0.f, 0.f, 0.f, 0.f};
        if (n < NN) {
            for (int k = q; k < NN; k += 4) {
                float a = A2g[n * NP + k];   // per-lane vector load, L1/L2-hot
                float4 xv = *(const float4*)(sX + k * 8);
                float x4 = sX[k * 8 + 4];
                acc[0] += a * xv.x; acc[1] += a * xv.y;
                acc[2] += a * xv.z; acc[3] += a * xv.w;
                acc[4] += a * x4;
            }
        }
#pragma unroll
        for (int c = 0; c < IN_CH; ++c) {
            acc[c] += __shfl_xor(acc[c], 1);
            acc[c] += __shfl_xor(acc[c], 2);
        }
        if (q == 0 && n < NN) {
#pragma unroll
            for (int c = 0; c < IN_CH; ++c) sY1[n * 8 + c] = acc[c];
        }
    }
    __syncthreads();

    const int nBase = w * 16;
    const int nEnd = (nBase + 16 < NN) ? (nBase + 16) : NN;

    // ---- H1[n][lane] = relu(b1 + Y1[n]·W1[lane]) for strip rows
    for (int n = nBase; n < nEnd; ++n) {
        float4 yv = *(const float4*)(sY1 + n * 8);
        float y4 = sY1[n * 8 + 4];
        float v = b1r + yv.x * w1r[0] + yv.y * w1r[1] + yv.z * w1r[2]
                      + yv.w * w1r[3] + y4 * w1r[4];
        sH1[n * NP + lane] = fmaxf(v, 0.f);
    }
    __syncthreads();

    // ---- G[k][lane] = H1[k]·W2[lane] for strip k; store transposed sGT[lane][k]
    for (int jb = 0; jb < 4; ++jb) {
        const int kb = nBase + 4 * jb;
        float gq[4];
#pragma unroll
        for (int j = 0; j < 4; ++j) {
            const int k = kb + j;           // wave-uniform
            float a0 = 0.f, a1 = 0.f, a2 = 0.f, a3 = 0.f;
            if (k < NN) {
                const float4* hr = (const float4*)(sH1 + k * NP);
#pragma unroll
                for (int i = 0; i < 16; ++i) {
                    float4 h = hr[i];
                    a0 += h.x * w2r[4 * i + 0];
                    a1 += h.y * w2r[4 * i + 1];
                    a2 += h.z * w2r[4 * i + 2];
                    a3 += h.w * w2r[4 * i + 3];
                }
            }
            gq[j] = (a0 + a1) + (a2 + a3);  // k>=62 -> 0 pad
        }
        *(float4*)(sGT + lane * GT_STRIDE + kb) = *(float4*)gq;
    }
    __syncthreads();

    // ---- hop-2 + relu + pool: G in registers, A2 rows via scalar loads
    float4 grv[16];
    {
        const float4* gt = (const float4*)(sGT + lane * GT_STRIDE);
#pragma unroll
        for (int i = 0; i < 16; ++i) grv[i] = gt[i];
    }
    float pooled = 0.f;
    for (int n = nBase; n < nEnd; ++n) {
        const float* an = A2g + n * NP;     // wave-uniform -> s_load
        float a0 = 0.f, a1 = 0.f, a2 = 0.f, a3 = 0.f;
#pragma unroll
        for (int i = 0; i < 16; ++i) {
            a0 += an[4 * i + 0] * grv[i].x;
            a1 += an[4 * i + 1] * grv[i].y;
            a2 += an[4 * i + 2] * grv[i].z;
            a3 += an[4 * i + 3] * grv[i].w;
        }
        pooled += fmaxf(b2r + ((a0 + a1) + (a2 + a3)), 0.f);
    }
    sPoolW[w * NP + lane] = pooled;
    __syncthreads();

    // ---- reduce pool over waves, then fc (3 outputs)
    if (w == 0) {
        float ph = sPoolW[lane] + sPoolW[64 + lane]
                 + sPoolW[128 + lane] + sPoolW[192 + lane];
        sPoolW[lane] = ph;
    }
    __syncthreads();
    if (t < OUT_CH) {
        float v = bfc[t];
        const float* wr = wfc + t * HID;
        for (int h = 0; h < HID; ++h) v += sPoolW[h] * wr[h];
        out[g * OUT_CH + t] = v;
    }
}

// ---------------------------------------------------------------------------
extern "C" void kernel_launch(void* const* d_in, const int* in_sizes, int n_in,
                              void* d_out, int out_size, void* d_ws, size_t ws_size,
                              hipStream_t stream) {
    const float* x   = (const float*)d_in[0];
    // d_in[1] = edge_index, d_in[2] = batch: fixed/deterministic -> unused
    const float* ewp = (const float*)d_in[3];
    const float* w1  = (const float*)d_in[4];
    const float* b1  = (const float*)d_in[5];
    const float* w2  = (const float*)d_in[6];
    const float* b2  = (const float*)d_in[7];
    const float* wfc = (const float*)d_in[8];
    const float* bfc = (const float*)d_in[9];
    float* out = (float*)d_out;

    float* A2g = (float*)d_ws;   // 62*64 floats

    setup_A2<<<NN, 64, 0, stream>>>(ewp, A2g);
    graph_net<<<NBATCH, 256, 0, stream>>>(x, A2g, w1, b1, w2, b2, wfc, bfc, out);
}

// Round 3
// 143.202 us; speedup vs baseline: 1.0490x; 1.0310x over previous
//
#include <hip/hip_runtime.h>

#define NN 62      // nodes per graph
#define NP 64      // padded row stride
#define NBATCH 1024
#define IN_CH 5
#define HID 64
#define OUT_CH 3
#define NTRIL 1953
#define GT_STRIDE 65   // odd stride: transpose write/read both bank-conflict-free

// ---------------------------------------------------------------------------
// setup: 62 blocks x 64 threads; every block rebuilds A = D^-1/2 W D^-1/2 in
// LDS (redundant, cheap), block n writes row n of A2 = A@A (64-wide, pad 0).
// ---------------------------------------------------------------------------
__global__ __launch_bounds__(64) void setup_A2(const float* __restrict__ p,
                                               float* __restrict__ A2g) {
    __shared__ float sA[NN * NP];
    __shared__ float sDinv[NN];
    const int lane = threadIdx.x;
    const int n = blockIdx.x;

    for (int i = lane; i < NN * NP; i += 64) sA[i] = 0.f;
    __syncthreads();

    for (int i = lane; i < NTRIL; i += 64) {
        int r = (int)((sqrtf(8.f * (float)i + 1.f) - 1.f) * 0.5f);
        while (r * (r + 1) / 2 > i) --r;
        while ((r + 1) * (r + 2) / 2 <= i) ++r;
        int c = i - r * (r + 1) / 2;
        float v = p[i];
        sA[r * NP + c] = v;
        sA[c * NP + r] = v;
    }
    __syncthreads();

    if (lane < NN) {
        float s = 0.f;
        for (int j = 0; j < NN; ++j) s += fabsf(sA[lane * NP + j]);
        sDinv[lane] = (s > 0.f) ? (1.0f / sqrtf(s)) : 0.f;
    }
    __syncthreads();

    for (int i = lane; i < NN * NP; i += 64) {
        int r = i >> 6, c = i & 63;
        float dc = (c < NN) ? sDinv[c] : 0.f;
        sA[i] = sDinv[r] * sA[i] * dc;   // pad cols stay 0
    }
    __syncthreads();

    float acc = 0.f;
    for (int k = 0; k < NN; ++k)
        acc += sA[n * NP + k] * sA[k * NP + lane];
    A2g[n * NP + lane] = acc;            // lane>=62 -> 0 (A pad cols are 0)
}

// ---------------------------------------------------------------------------
// main: 1024 blocks x 256 threads = 4 waves/graph.
// Stages Y1/H1/G: lane = NODE; all shared operands (X rows, W1, W2) are
// wave-uniform -> s_load (scalar cache), per-lane data in VGPRs, zero LDS.
// One conflict-free b32 transpose of G through LDS, then hop-2 with
// lane = CHANNEL (G column in regs, A2 rows via s_load).
// ---------------------------------------------------------------------------
__global__ __launch_bounds__(256, 4) void graph_net(
    const float* __restrict__ x_, const float* __restrict__ A2g_,
    const float* __restrict__ w1_, const float* __restrict__ b1_,
    const float* __restrict__ w2_, const float* __restrict__ b2_,
    const float* __restrict__ wfc, const float* __restrict__ bfc,
    float* __restrict__ out) {
    __shared__ float sGT[HID * GT_STRIDE];   // G transposed: [channel j][node n]
    __shared__ float sPool[4 * NP];

    const float* x   = (const float*)__builtin_assume_aligned(x_, 16);
    const float* A2g = (const float*)__builtin_assume_aligned(A2g_, 16);
    const float* w1  = (const float*)__builtin_assume_aligned(w1_, 16);
    const float* b1  = (const float*)__builtin_assume_aligned(b1_, 16);
    const float* w2  = (const float*)__builtin_assume_aligned(w2_, 16);
    const float* b2  = (const float*)__builtin_assume_aligned(b2_, 16);

    const int t = threadIdx.x;
    const int lane = t & 63;
    const int w = __builtin_amdgcn_readfirstlane(t >> 6);  // wave-uniform
    const int g = blockIdx.x;
    const float* xg = x + (size_t)g * (NN * IN_CH);

    // ---- A2 row (lane = node) into regs; lanes 62/63 read pad rows? n<62 only.
    float a2r[NP];
    {
        const int n = (lane < NN) ? lane : (NN - 1);   // clamp, results unused
        const float4* src = (const float4*)(A2g + n * NP);
#pragma unroll
        for (int i = 0; i < 16; ++i) {
            float4 v = src[i];
            a2r[4 * i + 0] = v.x; a2r[4 * i + 1] = v.y;
            a2r[4 * i + 2] = v.z; a2r[4 * i + 3] = v.w;
        }
    }

    // ---- Y1[lane][c] = sum_k a2r[k] * X[k][c]  (X via wave-uniform s_load)
    float y1[IN_CH] = {0.f, 0.f, 0.f, 0.f, 0.f};
#pragma unroll
    for (int k = 0; k < NN; ++k) {
        const float* xr = xg + k * IN_CH;
        float x0 = xr[0], x1 = xr[1], x2 = xr[2], x3 = xr[3], x4 = xr[4];
        float a = a2r[k];
        y1[0] += a * x0; y1[1] += a * x1; y1[2] += a * x2;
        y1[3] += a * x3; y1[4] += a * x4;
    }

    // ---- H1[lane][c] = relu(b1[c] + y1 · W1[c][:])  (W1/b1 via s_load)
    float h1[HID];
#pragma unroll
    for (int c = 0; c < HID; ++c) {
        const float* wr = w1 + c * IN_CH;
        float v = b1[c];
        v += y1[0] * wr[0]; v += y1[1] * wr[1]; v += y1[2] * wr[2];
        v += y1[3] * wr[3]; v += y1[4] * wr[4];
        h1[c] = fmaxf(v, 0.f);
    }

    // ---- G[lane][j] = h1 · W2[j][:] for wave's 16-channel strip; store to
    //      sGT[j][lane] (write banks consecutive -> conflict-free)
    const int jBase = w * 16;
#pragma unroll 2
    for (int jj = 0; jj < 16; ++jj) {
        const int j = jBase + jj;
        const float* wr = w2 + j * HID;     // wave-uniform -> s_load_dwordx16
        float a0 = 0.f, a1 = 0.f, a2 = 0.f, a3 = 0.f;
#pragma unroll
        for (int m = 0; m < HID; m += 4) {
            a0 += h1[m + 0] * wr[m + 0];
            a1 += h1[m + 1] * wr[m + 1];
            a2 += h1[m + 2] * wr[m + 2];
            a3 += h1[m + 3] * wr[m + 3];
        }
        if (lane < NN) sGT[j * GT_STRIDE + lane] = (a0 + a1) + (a2 + a3);
    }
    __syncthreads();

    // ---- hop-2 + relu + pool: lane = channel. G column in regs (2-way-free
    //      b32 reads), A2 rows via s_load.
    float grv[NN];
#pragma unroll
    for (int k = 0; k < NN; ++k) grv[k] = sGT[lane * GT_STRIDE + k];

    const float b2r = b2[lane];
    const int nBase = w * 16;
    const int nEnd = (nBase + 16 < NN) ? (nBase + 16) : NN;
    float pooled = 0.f;
#pragma unroll 2
    for (int n = nBase; n < nEnd; ++n) {
        const float* an = A2g + n * NP;     // wave-uniform -> s_load
        float a0 = 0.f, a1 = 0.f, a2 = 0.f, a3 = 0.f;
#pragma unroll
        for (int k = 0; k < 60; k += 4) {
            a0 += an[k + 0] * grv[k + 0];
            a1 += an[k + 1] * grv[k + 1];
            a2 += an[k + 2] * grv[k + 2];
            a3 += an[k + 3] * grv[k + 3];
        }
        a0 += an[60] * grv[60];
        a1 += an[61] * grv[61];
        pooled += fmaxf(b2r + ((a0 + a1) + (a2 + a3)), 0.f);
    }
    sPool[w * NP + lane] = pooled;
    __syncthreads();

    // ---- reduce pool over waves, then fc (3 outputs)
    if (w == 0) {
        float ph = sPool[lane] + sPool[64 + lane]
                 + sPool[128 + lane] + sPool[192 + lane];
        sPool[lane] = ph;
    }
    __syncthreads();
    if (t < OUT_CH) {
        float v = bfc[t];
        const float* wr = wfc + t * HID;
        for (int h = 0; h < HID; ++h) v += sPool[h] * wr[h];
        out[g * OUT_CH + t] = v;
    }
}

// ---------------------------------------------------------------------------
extern "C" void kernel_launch(void* const* d_in, const int* in_sizes, int n_in,
                              void* d_out, int out_size, void* d_ws, size_t ws_size,
                              hipStream_t stream) {
    const float* x   = (const float*)d_in[0];
    // d_in[1] = edge_index, d_in[2] = batch: fixed/deterministic -> unused
    const float* ewp = (const float*)d_in[3];
    const float* w1  = (const float*)d_in[4];
    const float* b1  = (const float*)d_in[5];
    const float* w2  = (const float*)d_in[6];
    const float* b2  = (const float*)d_in[7];
    const float* wfc = (const float*)d_in[8];
    const float* bfc = (const float*)d_in[9];
    float* out = (float*)d_out;

    float* A2g = (float*)d_ws;   // 62*64 floats

    setup_A2<<<NN, 64, 0, stream>>>(ewp, A2g);
    graph_net<<<NBATCH, 256, 0, stream>>>(x, A2g, w1, b1, w2, b2, wfc, bfc, out);
}